// Round 4
// baseline (485.199 us; speedup 1.0000x reference)
//
#include <hip/hip_runtime.h>

// Spatial correlation (cost volume), B=8 C=128 H=W=96, patch 9x9, 3x3 box, pad 1.
// out[b,di,dj,y,x] = sum_{i,j in 0..2} P[b,di,dj,y+i,x+j]
// P[b,di,dj,y',x'] = sum_c q_pad[y',x'] * k_pad[y'+di, x'+dj]   (padded 98x98 grid)
//
// R6: R5 ran at R3 speed (352us) with ALL pipes <30% busy -> the async
// prefetch still wasn't overlapping. Root cause theory: the double buffer
// was runtime-indexed (t[cb&1] vs t[(cb+1)&1]), so the compiler could not
// prove the in-flight global_load_lds LDS-writes don't alias the current
// buffer's ds_reads, and conservatively drained vmcnt(0) BEFORE the first
// ds_read of every pass -> fully serial (matches guide m99/m100: runtime-
// indexed LDS dbuf is neutral). Fix: two DISTINCT __shared__ statics t0/t1
// + pass loop unrolled by 2 so every stage/compute names its buffer at
// compile time; statically disjoint LDS objects let the stage loads stay
// in flight across the other buffer's reads. Only vmcnt drain left is the
// one inside __syncthreads, which sits AFTER compute.
// Kept from R5: direct-to-LDS staging (wave-uniform dest base + lane*4),
// precomputed offsets/masks, OOB slots pre-zeroed once, XCD swizzle
// (batch b -> XCD b; FETCH_SIZE 142->42.6 MB confirmed it works).

#define BATCH 8
#define CHN   128
#define IMG   96
#define IMG2  (IMG * IMG)   // 9216
#define TILE  16            // P-tile edge (padded-grid points) per block
#define OTILE 14            // output-tile edge per block (TILE - 2)
#define NC    8             // channels staged per pass
#define CHALF 64            // channels per block (2-way split)
#define NCB   (CHALF / NC)  // 8 passes
#define KT    24            // k-tile edge (TILE + 8)
#define QTP   16            // q-tile col stride
#define NTHR  512

struct Tiles {
  float qs[NC][TILE][QTP];   //  8192 B (flat 2048 floats = 4 chunks of 512)
  float ks[NC][KT][KT];      // 18432 B (flat 4608 floats = 9 chunks of 512)
};                           // 26624 B; t0+t1 = 53248 B -> 3 blocks/CU

__device__ __forceinline__ void async_ld4(const float* g, float* l) {
  __builtin_amdgcn_global_load_lds((const __attribute__((address_space(1))) unsigned int*)g,
                                   (__attribute__((address_space(3))) unsigned int*)l,
                                   4, 0, 0);
}

// Issue one pass's staging loads straight to LDS. FULL=interior block: no masks.
// LDS dest is the WAVE base; HW writes lane l at base + 4*l.
template <bool FULL>
__device__ __forceinline__ void issue_stage(const float* __restrict__ qcb,
                                            const float* __restrict__ kcb,
                                            Tiles& tb,
                                            const int (&qoff)[4], const int (&koff)[9],
                                            unsigned qm, unsigned km, int tid) {
  float* qf = &tb.qs[0][0][0] + (tid & ~63);   // wave-uniform base
  float* kf = &tb.ks[0][0][0] + (tid & ~63);
#pragma unroll
  for (int i = 0; i < 4; ++i)
    if (FULL || (qm & (1u << i))) async_ld4(qcb + qoff[i], qf + i * NTHR);
#pragma unroll
  for (int i = 0; i < 9; ++i)
    if (FULL || (km & (1u << i))) async_ld4(kcb + koff[i], kf + i * NTHR);
}

__device__ constexpr int di_lo_o(int OB, int d) {
  const int di = OB / 9 + d;
  return OB > di * 9 ? OB : di * 9;
}
__device__ constexpr int di_hi_o(int OB, int ON, int d) {
  const int di = OB / 9 + d;
  return (OB + ON) < (di * 9 + 9) ? (OB + ON) : (di * 9 + 9);
}
__device__ constexpr bool h_needed(int OB, int ON, int d, int h) {
  const int lo = di_lo_o(OB, d), hi = di_hi_o(OB, ON, d);
  if (lo >= hi) return false;
  const int di = OB / 9 + d;
  const int clo = lo - di * 9, chi = (hi - 1 - di * 9) + 3;
  return (4 * h <= chi) && (4 * h + 3 >= clo);
}

template <int OB, int ON, int d>
__device__ inline void do_row(const Tiles& t, int c, int py, int xg4,
                              const float (&qa)[4], float (&acc)[ON * 4]) {
  if constexpr (di_lo_o(OB, d) < di_hi_o(OB, ON, d)) {
    constexpr int DI0 = OB / 9;
    float kd[12];
    if constexpr (h_needed(OB, ON, d, 0)) *(float4*)&kd[0] = *(const float4*)&t.ks[c][py + DI0 + d][xg4 + 0];
    if constexpr (h_needed(OB, ON, d, 1)) *(float4*)&kd[4] = *(const float4*)&t.ks[c][py + DI0 + d][xg4 + 4];
    if constexpr (h_needed(OB, ON, d, 2)) *(float4*)&kd[8] = *(const float4*)&t.ks[c][py + DI0 + d][xg4 + 8];
#pragma unroll
    for (int oi = 0; oi < ON; ++oi) {
      if ((OB + oi) / 9 == DI0 + d) {            // constant-folded after unroll
        const int dj = (OB + oi) - ((OB + oi) / 9) * 9;
#pragma unroll
        for (int p = 0; p < 4; ++p)
          acc[oi * 4 + p] = __builtin_fmaf(qa[p], kd[dj + p], acc[oi * 4 + p]);
      }
    }
  }
}

template <int OB, int ON>
__device__ __forceinline__ void compute_pass(const Tiles& tc, int py, int xg4,
                                             float (&acc)[ON * 4]) {
#pragma unroll 2
  for (int c = 0; c < NC; ++c) {
    float qa[4];
    *(float4*)qa = *(const float4*)&tc.qs[c][py][xg4];
    do_row<OB, ON, 0>(tc, c, py, xg4, qa, acc);
    do_row<OB, ON, 1>(tc, c, py, xg4, qa, acc);
    do_row<OB, ON, 2>(tc, c, py, xg4, qa, acc);
  }
}

template <int OB, int ON, bool FULL>
__device__ void run(const float* __restrict__ qb, const float* __restrict__ kb,
                    float* __restrict__ out, Tiles& t0, Tiles& t1,
                    const int (&qoff)[4], const int (&koff)[9],
                    unsigned qm, unsigned km,
                    int b, int X0, int Y0, int tid, int lane) {
  const int xg  = lane & 3;    // 4 x-groups of 4 points = 16 cols
  const int py  = lane >> 2;   // 16 rows
  const int xg4 = xg * 4;

  float acc[ON * 4];
#pragma unroll
  for (int i = 0; i < ON * 4; ++i) acc[i] = 0.f;

  // Prologue: fill buffer 0 (async); barrier drains vmcnt.
  issue_stage<FULL>(qb, kb, t0, qoff, koff, qm, km, tid);
  __syncthreads();

  // Pass loop unrolled by 2: buffer identity is compile-time (t0 vs t1),
  // so in-flight stage writes provably don't alias current reads.
#pragma unroll 1
  for (int cb = 0; cb < NCB; cb += 2) {
    if (cb + 1 < NCB)
      issue_stage<FULL>(qb + (size_t)(cb + 1) * NC * IMG2,
                        kb + (size_t)(cb + 1) * NC * IMG2,
                        t1, qoff, koff, qm, km, tid);
    compute_pass<OB, ON>(t0, py, xg4, acc);
    __syncthreads();                     // t1 ready; t0 free to overwrite

    if (cb + 2 < NCB)
      issue_stage<FULL>(qb + (size_t)(cb + 2) * NC * IMG2,
                        kb + (size_t)(cb + 2) * NC * IMG2,
                        t0, qoff, koff, qm, km, tid);
    compute_pass<OB, ON>(t1, py, xg4, acc);
    if (cb + 2 < NCB) __syncthreads();   // t0 ready; t1 free (skip after last)
  }

  // Epilogue: 3x3 box sum entirely with shuffles (no LDS, no barriers).
  const int srcx = (xg < 3) ? (lane + 1) : lane;   // xg==3 values unused
  const int gy   = Y0 + py;
  const bool rowok = (py < OTILE) && (gy < IMG);
  float* obase = out + ((size_t)b * 81 * IMG + gy) * IMG + X0;
#pragma unroll
  for (int oi = 0; oi < ON; ++oi) {
    const float a0 = acc[oi * 4 + 0], a1 = acc[oi * 4 + 1];
    const float a2 = acc[oi * 4 + 2], a3 = acc[oi * 4 + 3];
    const float a0n = __shfl(a0, srcx);
    const float a1n = __shfl(a1, srcx);
    float s0 = a0 + a1 + a2;
    float s1 = a1 + a2 + a3;
    float s2 = a2 + a3 + a0n;
    float s3 = a3 + a0n + a1n;
    s0 += __shfl_down(s0, 4) + __shfl_down(s0, 8);
    s1 += __shfl_down(s1, 4) + __shfl_down(s1, 8);
    s2 += __shfl_down(s2, 4) + __shfl_down(s2, 8);
    s3 += __shfl_down(s3, 4) + __shfl_down(s3, 8);
    if (rowok) {
      const int o = OB + oi;
      float* orow = obase + (size_t)o * IMG * IMG;
      if (xg4 + 0 < OTILE && X0 + xg4 + 0 < IMG) atomicAdd(&orow[xg4 + 0], s0);
      if (xg4 + 1 < OTILE && X0 + xg4 + 1 < IMG) atomicAdd(&orow[xg4 + 1], s1);
      if (xg4 + 2 < OTILE && X0 + xg4 + 2 < IMG) atomicAdd(&orow[xg4 + 2], s2);
      if (xg4 + 3 < OTILE && X0 + xg4 + 3 < IMG) atomicAdd(&orow[xg4 + 3], s3);
    }
  }
}

template <bool FULL>
__device__ __forceinline__ void kern_body(const float* __restrict__ q,
                                          const float* __restrict__ k,
                                          float* __restrict__ out,
                                          Tiles& t0, Tiles& t1,
                                          int b, int cbase0, int X0, int Y0,
                                          int tid, int lane) {
  // Precompute per-thread staging offsets + validity masks ONCE.
  unsigned qm = 0, km = 0;
  int qoff[4], koff[9];
#pragma unroll
  for (int i = 0; i < 4; ++i) {
    const int s = i * NTHR + tid;
    const int c = s >> 8, rem = s & 255, rr = rem >> 4, col = rem & 15;
    const int gy = Y0 + rr - 1, gx = X0 + col - 1;
    qoff[i] = c * IMG2 + gy * IMG + gx;
    if ((unsigned)gy < IMG && (unsigned)gx < IMG) qm |= 1u << i; else qoff[i] = 0;
  }
#pragma unroll
  for (int i = 0; i < 9; ++i) {
    const int s = i * NTHR + tid;
    const int c = s / 576, rem = s - c * 576;
    const int r = rem / 24, col = rem - r * 24;
    const int gy = Y0 + r - 5, gx = X0 + col - 5;
    koff[i] = c * IMG2 + gy * IMG + gx;
    if ((unsigned)gy < IMG && (unsigned)gx < IMG) km |= 1u << i; else koff[i] = 0;
  }

  // Zero the never-loaded (OOB) LDS slots once, for both buffers.
  if constexpr (!FULL) {
    float* qf0 = &t0.qs[0][0][0]; float* qf1 = &t1.qs[0][0][0];
    float* kf0 = &t0.ks[0][0][0]; float* kf1 = &t1.ks[0][0][0];
#pragma unroll
    for (int i = 0; i < 4; ++i)
      if (!(qm & (1u << i))) { qf0[i * NTHR + tid] = 0.f; qf1[i * NTHR + tid] = 0.f; }
#pragma unroll
    for (int i = 0; i < 9; ++i)
      if (!(km & (1u << i))) { kf0[i * NTHR + tid] = 0.f; kf1[i * NTHR + tid] = 0.f; }
  }

  const float* qb = q + (size_t)(b * CHN + cbase0) * IMG2;
  const float* kb = k + (size_t)(b * CHN + cbase0) * IMG2;

  const int w = tid >> 6;
  // 8 waves x (11,10,...,10) offsets; every window spans exactly 2 di rows.
  if (w == 0)      run<0,  11, FULL>(qb, kb, out, t0, t1, qoff, koff, qm, km, b, X0, Y0, tid, lane);
  else if (w == 1) run<11, 10, FULL>(qb, kb, out, t0, t1, qoff, koff, qm, km, b, X0, Y0, tid, lane);
  else if (w == 2) run<21, 10, FULL>(qb, kb, out, t0, t1, qoff, koff, qm, km, b, X0, Y0, tid, lane);
  else if (w == 3) run<31, 10, FULL>(qb, kb, out, t0, t1, qoff, koff, qm, km, b, X0, Y0, tid, lane);
  else if (w == 4) run<41, 10, FULL>(qb, kb, out, t0, t1, qoff, koff, qm, km, b, X0, Y0, tid, lane);
  else if (w == 5) run<51, 10, FULL>(qb, kb, out, t0, t1, qoff, koff, qm, km, b, X0, Y0, tid, lane);
  else if (w == 6) run<61, 10, FULL>(qb, kb, out, t0, t1, qoff, koff, qm, km, b, X0, Y0, tid, lane);
  else             run<71, 10, FULL>(qb, kb, out, t0, t1, qoff, koff, qm, km, b, X0, Y0, tid, lane);
}

__global__ __launch_bounds__(NTHR, 4) void spatial_corr_kernel(const float* __restrict__ q,
                                                               const float* __restrict__ k,
                                                               float* __restrict__ out) {
  __shared__ Tiles t0;   // distinct statics: compile-time non-aliasing
  __shared__ Tiles t1;
  const int tid  = threadIdx.x;
  const int lane = tid & 63;

  // XCD swizzle: 784 = 8 * 98; XCD g owns logical ids [98g, 98g+98) -> exactly
  // batch g (both channel halves, all 49 tiles) -> q/k of one batch hot in L2.
  int id = blockIdx.x;
  id = (id & 7) * 98 + (id >> 3);
  const int bx = id % 7; id /= 7;
  const int by = id % 7; id /= 7;
  const int bz = id;                      // 0..15
  const int b      = bz >> 1;
  const int cbase0 = (bz & 1) * CHALF;
  const int X0 = bx * OTILE;
  const int Y0 = by * OTILE;

  const bool full = (bx >= 1) && (bx <= 5) && (by >= 1) && (by <= 5);
  if (full) kern_body<true >(q, k, out, t0, t1, b, cbase0, X0, Y0, tid, lane);
  else      kern_body<false>(q, k, out, t0, t1, b, cbase0, X0, Y0, tid, lane);
}

extern "C" void kernel_launch(void* const* d_in, const int* in_sizes, int n_in,
                              void* d_out, int out_size, void* d_ws, size_t ws_size,
                              hipStream_t stream) {
  const float* q = (const float*)d_in[0];
  const float* k = (const float*)d_in[1];
  // d_in[2] (value) is unused by the reference output.
  float* out = (float*)d_out;
  hipMemsetAsync(out, 0, (size_t)out_size * sizeof(float), stream);
  dim3 grid(7 * 7 * BATCH * 2);   // 1D so the XCD swizzle controls placement
  dim3 block(NTHR);
  hipLaunchKernelGGL(spatial_corr_kernel, grid, block, 0, stream, q, k, out);
}

// Round 7
// 232.092 us; speedup vs baseline: 2.0905x; 2.0905x over previous
//
#include <hip/hip_runtime.h>

// Spatial correlation (cost volume), B=8 C=128 H=W=96, patch 9x9, 3x3 box, pad 1.
// out[b,di,dj,y,x] = sum_{i,j in 0..2} P[b,di,dj,y+i,x+j]
// P[b,di,dj,y',x'] = sum_c q_pad[y',x'] * k_pad[y'+di, x'+dj]   (padded 98x98 grid)
//
// R8: R7/R7b (workspace + templated __global__ kernels + 32 instantiations)
// died twice at the container layer while R2-R6 all ran -> avoid the two
// features unique to R7 (templated kernel symbols, 2x code size). The
// atomic-elimination theory is still the one under test:
//   R3/R5/R6 pipeline variants all flat ~350us, all pipes <30% busy;
//   WRITE_SIZE 251 MB vs 24 MB output = 10x amplification from 12.4M fp32
//   atomicAdds -> L2 RMW serialization is the suspected shared floor.
// Change vs verified R5 (ONE structural variable): drop the 2-way channel
// split. One block owns one output tile and loops all 128 channels in 16
// passes -> exactly one writer per output element -> plain predicated
// stores. No atomics, no memset, no workspace, no second kernel, no
// templated __global__. Grid 392 = 8 XCDs x 49; XCD swizzle gives batch b
// -> XCD b. Staged bytes unchanged (halves loaded disjoint channels).
// Kept from R5 (proven, absmax 0.5): direct-to-LDS async staging with
// wave-uniform dest base, runtime-indexed double buffer w/ single barrier
// per pass, precomputed offsets/masks, OOB LDS slots pre-zeroed.

#define BATCH 8
#define CHN   128
#define IMG   96
#define IMG2  (IMG * IMG)   // 9216
#define TILE  16            // P-tile edge (padded-grid points) per block
#define OTILE 14            // output-tile edge per block (TILE - 2)
#define NC    8             // channels staged per pass
#define NCB   (CHN / NC)    // 16 passes (all 128 channels in one block)
#define KT    24            // k-tile edge (TILE + 8)
#define QTP   16            // q-tile col stride
#define NTHR  512
#define NBLK  (7 * 7 * BATCH)   // 392 = 8 * 49

struct Tiles {
  float qs[NC][TILE][QTP];   //  8192 B (flat 2048 floats = 4 chunks of 512)
  float ks[NC][KT][KT];      // 18432 B (flat 4608 floats = 9 chunks of 512)
};                           // 26624 B; t[2] = 53248 B -> 3 blocks/CU

__device__ __forceinline__ void async_ld4(const float* g, float* l) {
  __builtin_amdgcn_global_load_lds((const __attribute__((address_space(1))) unsigned int*)g,
                                   (__attribute__((address_space(3))) unsigned int*)l,
                                   4, 0, 0);
}

// Issue one pass's staging loads straight to LDS. FULL=interior block: no masks.
// LDS dest is the WAVE base; HW writes lane l at base + 4*l.
template <bool FULL>
__device__ __forceinline__ void issue_stage(const float* __restrict__ qcb,
                                            const float* __restrict__ kcb,
                                            Tiles& tb,
                                            const int (&qoff)[4], const int (&koff)[9],
                                            unsigned qm, unsigned km, int tid) {
  float* qf = &tb.qs[0][0][0] + (tid & ~63);   // wave-uniform base
  float* kf = &tb.ks[0][0][0] + (tid & ~63);
#pragma unroll
  for (int i = 0; i < 4; ++i)
    if (FULL || (qm & (1u << i))) async_ld4(qcb + qoff[i], qf + i * NTHR);
#pragma unroll
  for (int i = 0; i < 9; ++i)
    if (FULL || (km & (1u << i))) async_ld4(kcb + koff[i], kf + i * NTHR);
}

__device__ constexpr int di_lo_o(int OB, int d) {
  const int di = OB / 9 + d;
  return OB > di * 9 ? OB : di * 9;
}
__device__ constexpr int di_hi_o(int OB, int ON, int d) {
  const int di = OB / 9 + d;
  return (OB + ON) < (di * 9 + 9) ? (OB + ON) : (di * 9 + 9);
}
__device__ constexpr bool h_needed(int OB, int ON, int d, int h) {
  const int lo = di_lo_o(OB, d), hi = di_hi_o(OB, ON, d);
  if (lo >= hi) return false;
  const int di = OB / 9 + d;
  const int clo = lo - di * 9, chi = (hi - 1 - di * 9) + 3;
  return (4 * h <= chi) && (4 * h + 3 >= clo);
}

template <int OB, int ON, int d>
__device__ inline void do_row(const Tiles& t, int c, int py, int xg4,
                              const float (&qa)[4], float (&acc)[ON * 4]) {
  if constexpr (di_lo_o(OB, d) < di_hi_o(OB, ON, d)) {
    constexpr int DI0 = OB / 9;
    float kd[12];
    if constexpr (h_needed(OB, ON, d, 0)) *(float4*)&kd[0] = *(const float4*)&t.ks[c][py + DI0 + d][xg4 + 0];
    if constexpr (h_needed(OB, ON, d, 1)) *(float4*)&kd[4] = *(const float4*)&t.ks[c][py + DI0 + d][xg4 + 4];
    if constexpr (h_needed(OB, ON, d, 2)) *(float4*)&kd[8] = *(const float4*)&t.ks[c][py + DI0 + d][xg4 + 8];
#pragma unroll
    for (int oi = 0; oi < ON; ++oi) {
      if ((OB + oi) / 9 == DI0 + d) {            // constant-folded after unroll
        const int dj = (OB + oi) - ((OB + oi) / 9) * 9;
#pragma unroll
        for (int p = 0; p < 4; ++p)
          acc[oi * 4 + p] = __builtin_fmaf(qa[p], kd[dj + p], acc[oi * 4 + p]);
      }
    }
  }
}

template <int OB, int ON, bool FULL>
__device__ void run(const float* __restrict__ qb, const float* __restrict__ kb,
                    float* __restrict__ out, Tiles* __restrict__ t,
                    const int (&qoff)[4], const int (&koff)[9],
                    unsigned qm, unsigned km,
                    int b, int X0, int Y0, int tid, int lane) {
  const int xg  = lane & 3;    // 4 x-groups of 4 points = 16 cols
  const int py  = lane >> 2;   // 16 rows
  const int xg4 = xg * 4;

  float acc[ON * 4];
#pragma unroll
  for (int i = 0; i < ON * 4; ++i) acc[i] = 0.f;

  // Prologue: fill buffer 0 (async); barrier drains vmcnt.
  issue_stage<FULL>(qb, kb, t[0], qoff, koff, qm, km, tid);
  __syncthreads();

  for (int cb = 0; cb < NCB; ++cb) {
    if (cb + 1 < NCB)
      issue_stage<FULL>(qb + (size_t)(cb + 1) * NC * IMG2,
                        kb + (size_t)(cb + 1) * NC * IMG2,
                        t[(cb + 1) & 1], qoff, koff, qm, km, tid);
    const Tiles& tc = t[cb & 1];
#pragma unroll 2
    for (int c = 0; c < NC; ++c) {
      float qa[4];
      *(float4*)qa = *(const float4*)&tc.qs[c][py][xg4];
      do_row<OB, ON, 0>(tc, c, py, xg4, qa, acc);
      do_row<OB, ON, 1>(tc, c, py, xg4, qa, acc);
      do_row<OB, ON, 2>(tc, c, py, xg4, qa, acc);
    }
    __syncthreads();                     // single barrier per pass (drains vmcnt)
  }

  // Epilogue: 3x3 box sum entirely with shuffles (no LDS, no barriers).
  // This block is the EXCLUSIVE owner of its output tile: plain stores.
  const int srcx = (xg < 3) ? (lane + 1) : lane;   // xg==3 values unused
  const int gy   = Y0 + py;
  const bool rowok = (py < OTILE) && (gy < IMG);
  float* obase = out + ((size_t)b * 81 * IMG + gy) * IMG + X0;
#pragma unroll
  for (int oi = 0; oi < ON; ++oi) {
    const float a0 = acc[oi * 4 + 0], a1 = acc[oi * 4 + 1];
    const float a2 = acc[oi * 4 + 2], a3 = acc[oi * 4 + 3];
    const float a0n = __shfl(a0, srcx);
    const float a1n = __shfl(a1, srcx);
    float s0 = a0 + a1 + a2;
    float s1 = a1 + a2 + a3;
    float s2 = a2 + a3 + a0n;
    float s3 = a3 + a0n + a1n;
    s0 += __shfl_down(s0, 4) + __shfl_down(s0, 8);
    s1 += __shfl_down(s1, 4) + __shfl_down(s1, 8);
    s2 += __shfl_down(s2, 4) + __shfl_down(s2, 8);
    s3 += __shfl_down(s3, 4) + __shfl_down(s3, 8);
    if (rowok) {
      const int o = OB + oi;
      float* orow = obase + (size_t)o * IMG * IMG;
      if (xg4 + 0 < OTILE && X0 + xg4 + 0 < IMG) orow[xg4 + 0] = s0;
      if (xg4 + 1 < OTILE && X0 + xg4 + 1 < IMG) orow[xg4 + 1] = s1;
      if (xg4 + 2 < OTILE && X0 + xg4 + 2 < IMG) orow[xg4 + 2] = s2;
      if (xg4 + 3 < OTILE && X0 + xg4 + 3 < IMG) orow[xg4 + 3] = s3;
    }
  }
}

template <bool FULL>
__device__ __forceinline__ void kern_body(const float* __restrict__ q,
                                          const float* __restrict__ k,
                                          float* __restrict__ out, Tiles* t,
                                          int b, int X0, int Y0,
                                          int tid, int lane) {
  // Precompute per-thread staging offsets + validity masks ONCE.
  unsigned qm = 0, km = 0;
  int qoff[4], koff[9];
#pragma unroll
  for (int i = 0; i < 4; ++i) {
    const int s = i * NTHR + tid;
    const int c = s >> 8, rem = s & 255, rr = rem >> 4, col = rem & 15;
    const int gy = Y0 + rr - 1, gx = X0 + col - 1;
    qoff[i] = c * IMG2 + gy * IMG + gx;
    if ((unsigned)gy < IMG && (unsigned)gx < IMG) qm |= 1u << i; else qoff[i] = 0;
  }
#pragma unroll
  for (int i = 0; i < 9; ++i) {
    const int s = i * NTHR + tid;
    const int c = s / 576, rem = s - c * 576;
    const int r = rem / 24, col = rem - r * 24;
    const int gy = Y0 + r - 5, gx = X0 + col - 5;
    koff[i] = c * IMG2 + gy * IMG + gx;
    if ((unsigned)gy < IMG && (unsigned)gx < IMG) km |= 1u << i; else koff[i] = 0;
  }

  // Zero the never-loaded (OOB) LDS slots once, for both buffers.
  if constexpr (!FULL) {
    float* qf0 = &t[0].qs[0][0][0]; float* qf1 = &t[1].qs[0][0][0];
    float* kf0 = &t[0].ks[0][0][0]; float* kf1 = &t[1].ks[0][0][0];
#pragma unroll
    for (int i = 0; i < 4; ++i)
      if (!(qm & (1u << i))) { qf0[i * NTHR + tid] = 0.f; qf1[i * NTHR + tid] = 0.f; }
#pragma unroll
    for (int i = 0; i < 9; ++i)
      if (!(km & (1u << i))) { kf0[i * NTHR + tid] = 0.f; kf1[i * NTHR + tid] = 0.f; }
  }

  const float* qb = q + (size_t)b * CHN * IMG2;
  const float* kb = k + (size_t)b * CHN * IMG2;

  const int w = tid >> 6;
  // 8 waves x (11,10,...,10) offsets; every window spans exactly 2 di rows.
  if (w == 0)      run<0,  11, FULL>(qb, kb, out, t, qoff, koff, qm, km, b, X0, Y0, tid, lane);
  else if (w == 1) run<11, 10, FULL>(qb, kb, out, t, qoff, koff, qm, km, b, X0, Y0, tid, lane);
  else if (w == 2) run<21, 10, FULL>(qb, kb, out, t, qoff, koff, qm, km, b, X0, Y0, tid, lane);
  else if (w == 3) run<31, 10, FULL>(qb, kb, out, t, qoff, koff, qm, km, b, X0, Y0, tid, lane);
  else if (w == 4) run<41, 10, FULL>(qb, kb, out, t, qoff, koff, qm, km, b, X0, Y0, tid, lane);
  else if (w == 5) run<51, 10, FULL>(qb, kb, out, t, qoff, koff, qm, km, b, X0, Y0, tid, lane);
  else if (w == 6) run<61, 10, FULL>(qb, kb, out, t, qoff, koff, qm, km, b, X0, Y0, tid, lane);
  else             run<71, 10, FULL>(qb, kb, out, t, qoff, koff, qm, km, b, X0, Y0, tid, lane);
}

__global__ __launch_bounds__(NTHR, 4) void spatial_corr_kernel(const float* __restrict__ q,
                                                               const float* __restrict__ k,
                                                               float* __restrict__ out) {
  __shared__ Tiles t[2];
  const int tid  = threadIdx.x;
  const int lane = tid & 63;

  // XCD swizzle: 392 = 8 * 49; XCD g owns logical ids [49g, 49g+49) = all 49
  // tiles of batch g -> q/k of one batch hot in that XCD's 4MB L2.
  int id = blockIdx.x;
  id = (id & 7) * 49 + (id >> 3);
  const int bx = id % 7; id /= 7;
  const int by = id % 7; id /= 7;
  const int b  = id;                      // 0..7
  const int X0 = bx * OTILE;
  const int Y0 = by * OTILE;

  const bool full = (bx >= 1) && (bx <= 5) && (by >= 1) && (by <= 5);
  if (full) kern_body<true >(q, k, out, t, b, X0, Y0, tid, lane);
  else      kern_body<false>(q, k, out, t, b, X0, Y0, tid, lane);
}

extern "C" void kernel_launch(void* const* d_in, const int* in_sizes, int n_in,
                              void* d_out, int out_size, void* d_ws, size_t ws_size,
                              hipStream_t stream) {
  const float* q = (const float*)d_in[0];
  const float* k = (const float*)d_in[1];
  // d_in[2] (value) is unused by the reference output.
  float* out = (float*)d_out;
  // Every output element has exactly one writer -> no memset, no atomics.
  dim3 grid(NBLK);
  dim3 block(NTHR);
  hipLaunchKernelGGL(spatial_corr_kernel, grid, block, 0, stream, q, k, out);
}